// Round 1
// baseline (164.987 us; speedup 1.0000x reference)
//
#include <hip/hip_runtime.h>
#include <hip/hip_bf16.h>
#include <stdint.h>

#define H 512
#define F 2048
#define E 8
#define NTOK 8192

#define BM 128
#define BN 128
#define BK 64
#define SA 72   // LDS row stride in bf16 elems (64 + 8 pad -> 144B rows, conflict-free)

typedef __bf16 bf16x8 __attribute__((ext_vector_type(8)));
typedef float f32x4 __attribute__((ext_vector_type(4)));

__device__ __forceinline__ unsigned short f2bf(float f) {
    unsigned u = __builtin_bit_cast(unsigned, f);
    u += 0x7FFFu + ((u >> 16) & 1u);
    return (unsigned short)(u >> 16);
}

// ---------- x fp32 -> bf16 ----------
__global__ void cvt_x_kernel(const float* __restrict__ x, unsigned short* __restrict__ xbf) {
    int i = blockIdx.x * blockDim.x + threadIdx.x;  // one thread per 8 elems, exact grid
    const float4* x4 = (const float4*)x;
    float4 a = x4[i * 2], b = x4[i * 2 + 1];
    uint4 u;
    u.x = (unsigned)f2bf(a.x) | ((unsigned)f2bf(a.y) << 16);
    u.y = (unsigned)f2bf(a.z) | ((unsigned)f2bf(a.w) << 16);
    u.z = (unsigned)f2bf(b.x) | ((unsigned)f2bf(b.y) << 16);
    u.w = (unsigned)f2bf(b.z) | ((unsigned)f2bf(b.w) << 16);
    ((uint4*)xbf)[i] = u;
}

// ---------- transpose + convert: src [batch][R][C] fp32 -> dst [batch][C][R] bf16 ----------
__global__ void transpose_cvt_kernel(const float* __restrict__ src, unsigned short* __restrict__ dst,
                                     int R, int C) {
    __shared__ unsigned short t[64][68];
    int b = blockIdx.z;
    const float* s = src + (size_t)b * R * C;
    unsigned short* d = dst + (size_t)b * R * C;
    int r0 = blockIdx.y * 64, c0 = blockIdx.x * 64;
    int tid = threadIdx.x;
    #pragma unroll
    for (int p = 0; p < 16; ++p) {
        int id = p * 256 + tid;
        int r = id >> 6, c = id & 63;
        t[r][c] = f2bf(s[(size_t)(r0 + r) * C + (c0 + c)]);
    }
    __syncthreads();
    #pragma unroll
    for (int p = 0; p < 16; ++p) {
        int id = p * 256 + tid;
        int rr = id >> 6, cc = id & 63;   // output row c0+rr, output col r0+cc
        d[(size_t)(c0 + rr) * R + (r0 + cc)] = t[cc][rr];
    }
}

// ---------- router: logits, softmax, argmax, gate, expert lists, lb partials ----------
__global__ void router_kernel(const float* __restrict__ x, const float* __restrict__ Wg,
                              float* __restrict__ gate, int* __restrict__ list,
                              int* __restrict__ cnt, float* __restrict__ pprob) {
    __shared__ float wg[H * E];        // 16 KB
    __shared__ float lg[32][8];        // logits then probs
    __shared__ int am_l[32];
    __shared__ int rank_l[32];
    __shared__ int eb[8];
    int tid = threadIdx.x;

    #pragma unroll
    for (int p = 0; p < 16; ++p) wg[p * 256 + tid] = Wg[p * 256 + tid];
    __syncthreads();

    int tl = tid >> 3, e = tid & 7;
    int token = blockIdx.x * 32 + tl;
    const float4* x4 = (const float4*)(x + (size_t)token * H);
    float acc = 0.f;
    for (int kq = 0; kq < 128; ++kq) {
        float4 v = x4[kq];
        acc += v.x * wg[(kq * 4 + 0) * 8 + e];
        acc += v.y * wg[(kq * 4 + 1) * 8 + e];
        acc += v.z * wg[(kq * 4 + 2) * 8 + e];
        acc += v.w * wg[(kq * 4 + 3) * 8 + e];
    }
    lg[tl][e] = acc;
    __syncthreads();

    if (tid < 32) {
        float l[8];
        #pragma unroll
        for (int q = 0; q < 8; ++q) l[q] = lg[tid][q];
        float mx = l[0];
        #pragma unroll
        for (int q = 1; q < 8; ++q) mx = fmaxf(mx, l[q]);
        float p[8]; float s = 0.f;
        #pragma unroll
        for (int q = 0; q < 8; ++q) { p[q] = expf(l[q] - mx); s += p[q]; }
        int am = 0; float best = l[0];
        #pragma unroll
        for (int q = 1; q < 8; ++q) if (l[q] > best) { best = l[q]; am = q; }
        float inv = 1.f / s;
        #pragma unroll
        for (int q = 0; q < 8; ++q) lg[tid][q] = p[q] * inv;
        float sp = p[am] * inv;
        gate[blockIdx.x * 32 + tid] = sp / (sp + 1e-8f);
        am_l[tid] = am;
    }
    __syncthreads();

    if (tid < 8) {
        float s = 0.f;
        for (int i = 0; i < 32; ++i) s += lg[i][tid];
        pprob[blockIdx.x * 8 + tid] = s;
        int c = 0;
        for (int i = 0; i < 32; ++i) if (am_l[i] == tid) rank_l[i] = c++;
        eb[tid] = atomicAdd(&cnt[tid], c);
    }
    __syncthreads();

    if (tid < 32) {
        int e2 = am_l[tid];
        list[e2 * NTOK + eb[e2] + rank_l[tid]] = blockIdx.x * 32 + tid;
    }
}

// ---------- GEMM1: h = relu(x_gathered @ W1t^T + b1) -> hbf ----------
__global__ __launch_bounds__(256) void gemm1_kernel(
    const unsigned short* __restrict__ xbf,   // [NTOK][H] bf16
    const unsigned short* __restrict__ w1t,   // [E][F][H] bf16 (n-major)
    const float* __restrict__ b1,             // [E][F]
    const int* __restrict__ list, const int* __restrict__ cnt,
    unsigned short* __restrict__ hbf)         // [NTOK][F]
{
    int e = blockIdx.z;
    int m0 = blockIdx.y * BM;
    int count = cnt[e];
    if (m0 >= count) return;
    int n0 = blockIdx.x * BN;

    __shared__ unsigned short Al[BM * SA];
    __shared__ unsigned short Bl[BN * SA];
    __shared__ int toks[BM];
    int tid = threadIdx.x;
    if (tid < BM) {
        int m = m0 + tid;
        toks[tid] = (m < count) ? list[e * NTOK + m] : -1;
    }
    __syncthreads();

    f32x4 acc[4][4] = {};
    int lane = tid & 63;
    int w = tid >> 6;
    int mb = (w >> 1) * 64;
    int nb = (w & 1) * 64;
    int lr = lane & 15;
    int lk = (lane >> 4) * 8;

    for (int k0 = 0; k0 < H; k0 += BK) {
        #pragma unroll
        for (int c = 0; c < 4; ++c) {
            int chunk = c * 256 + tid;
            int row = chunk >> 3, off = chunk & 7;
            int tk = toks[row];
            int tkc = tk < 0 ? 0 : tk;
            uint4 va = *(const uint4*)(xbf + (size_t)tkc * H + k0 + off * 8);
            *(uint4*)(&Al[row * SA + off * 8]) = va;
            uint4 vb = *(const uint4*)(w1t + ((size_t)e * F + n0 + row) * H + k0 + off * 8);
            *(uint4*)(&Bl[row * SA + off * 8]) = vb;
        }
        __syncthreads();
        #pragma unroll
        for (int kk = 0; kk < 2; ++kk) {
            bf16x8 a[4], b[4];
            #pragma unroll
            for (int i = 0; i < 4; ++i)
                a[i] = *(const bf16x8*)(&Al[(mb + i * 16 + lr) * SA + kk * 32 + lk]);
            #pragma unroll
            for (int j = 0; j < 4; ++j)
                b[j] = *(const bf16x8*)(&Bl[(nb + j * 16 + lr) * SA + kk * 32 + lk]);
            #pragma unroll
            for (int i = 0; i < 4; ++i)
                #pragma unroll
                for (int j = 0; j < 4; ++j)
                    acc[i][j] = __builtin_amdgcn_mfma_f32_16x16x32_bf16(a[i], b[j], acc[i][j], 0, 0, 0);
        }
        __syncthreads();
    }

    int rbase = (lane >> 4) * 4;
    #pragma unroll
    for (int j = 0; j < 4; ++j) {
        int gcol = n0 + nb + j * 16 + lr;
        float bias = b1[e * F + gcol];
        #pragma unroll
        for (int i = 0; i < 4; ++i) {
            #pragma unroll
            for (int r = 0; r < 4; ++r) {
                int rl = mb + i * 16 + rbase + r;
                int tk = toks[rl];
                if (tk >= 0) {
                    float v = acc[i][j][r] + bias;
                    v = v > 0.f ? v : 0.f;
                    hbf[(size_t)tk * F + gcol] = f2bf(v);
                }
            }
        }
    }
}

// ---------- GEMM2: out = gate * (h_gathered @ W2t^T + b2), scattered ----------
__global__ __launch_bounds__(256) void gemm2_kernel(
    const unsigned short* __restrict__ hbf,   // [NTOK][F] bf16
    const unsigned short* __restrict__ w2t,   // [E][H][F] bf16 (n-major)
    const float* __restrict__ b2,             // [E][H]
    const int* __restrict__ list, const int* __restrict__ cnt,
    const float* __restrict__ gate,
    float* __restrict__ out)                  // [NTOK][H]
{
    int e = blockIdx.z;
    int m0 = blockIdx.y * BM;
    int count = cnt[e];
    if (m0 >= count) return;
    int n0 = blockIdx.x * BN;

    __shared__ unsigned short Al[BM * SA];
    __shared__ unsigned short Bl[BN * SA];
    __shared__ int toks[BM];
    __shared__ float gts[BM];
    int tid = threadIdx.x;
    if (tid < BM) {
        int m = m0 + tid;
        int tk = (m < count) ? list[e * NTOK + m] : -1;
        toks[tid] = tk;
        gts[tid] = (tk >= 0) ? gate[tk] : 0.f;
    }
    __syncthreads();

    f32x4 acc[4][4] = {};
    int lane = tid & 63;
    int w = tid >> 6;
    int mb = (w >> 1) * 64;
    int nb = (w & 1) * 64;
    int lr = lane & 15;
    int lk = (lane >> 4) * 8;

    for (int k0 = 0; k0 < F; k0 += BK) {
        #pragma unroll
        for (int c = 0; c < 4; ++c) {
            int chunk = c * 256 + tid;
            int row = chunk >> 3, off = chunk & 7;
            int tk = toks[row];
            int tkc = tk < 0 ? 0 : tk;
            uint4 va = *(const uint4*)(hbf + (size_t)tkc * F + k0 + off * 8);
            *(uint4*)(&Al[row * SA + off * 8]) = va;
            uint4 vb = *(const uint4*)(w2t + ((size_t)e * H + n0 + row) * F + k0 + off * 8);
            *(uint4*)(&Bl[row * SA + off * 8]) = vb;
        }
        __syncthreads();
        #pragma unroll
        for (int kk = 0; kk < 2; ++kk) {
            bf16x8 a[4], b[4];
            #pragma unroll
            for (int i = 0; i < 4; ++i)
                a[i] = *(const bf16x8*)(&Al[(mb + i * 16 + lr) * SA + kk * 32 + lk]);
            #pragma unroll
            for (int j = 0; j < 4; ++j)
                b[j] = *(const bf16x8*)(&Bl[(nb + j * 16 + lr) * SA + kk * 32 + lk]);
            #pragma unroll
            for (int i = 0; i < 4; ++i)
                #pragma unroll
                for (int j = 0; j < 4; ++j)
                    acc[i][j] = __builtin_amdgcn_mfma_f32_16x16x32_bf16(a[i], b[j], acc[i][j], 0, 0, 0);
        }
        __syncthreads();
    }

    int rbase = (lane >> 4) * 4;
    #pragma unroll
    for (int j = 0; j < 4; ++j) {
        int gcol = n0 + nb + j * 16 + lr;
        float bias = b2[e * H + gcol];
        #pragma unroll
        for (int i = 0; i < 4; ++i) {
            #pragma unroll
            for (int r = 0; r < 4; ++r) {
                int rl = mb + i * 16 + rbase + r;
                int tk = toks[rl];
                if (tk >= 0) {
                    out[(size_t)tk * H + gcol] = gts[rl] * (acc[i][j][r] + bias);
                }
            }
        }
    }
}

// ---------- lb loss ----------
__global__ void lb_kernel(const float* __restrict__ pprob, const int* __restrict__ cnt,
                          float* __restrict__ outlb) {
    __shared__ float s[8];
    int t = threadIdx.x;
    if (t < 8) {
        float acc = 0.f;
        for (int i = 0; i < 256; ++i) acc += pprob[i * 8 + t];
        s[t] = acc * (float)cnt[t];
    }
    __syncthreads();
    if (t == 0) {
        float tot = 0.f;
        for (int q = 0; q < 8; ++q) tot += s[q];
        outlb[0] = tot * (8.0f / ((float)NTOK * (float)NTOK));
    }
}

extern "C" void kernel_launch(void* const* d_in, const int* in_sizes, int n_in,
                              void* d_out, int out_size, void* d_ws, size_t ws_size,
                              hipStream_t stream) {
    const float* x  = (const float*)d_in[0];
    const float* Wg = (const float*)d_in[1];
    const float* W1 = (const float*)d_in[2];
    const float* b1 = (const float*)d_in[3];
    const float* W2 = (const float*)d_in[4];
    const float* b2 = (const float*)d_in[5];
    float* out = (float*)d_out;

    char* ws = (char*)d_ws;
    unsigned short* xbf = (unsigned short*)(ws + 0);          //  8 MB
    unsigned short* w1t = (unsigned short*)(ws + 8388608);    // 16 MB
    unsigned short* w2t = (unsigned short*)(ws + 25165824);   // 16 MB
    unsigned short* hbf = (unsigned short*)(ws + 41943040);   // 32 MB
    float* gate = (float*)(ws + 75497472);                    // 32 KB
    int* list   = (int*)(ws + 75530240);                      // 256 KB
    int* cnt    = (int*)(ws + 75792384);                      // 32 B
    float* pprob= (float*)(ws + 75792448);                    // 8 KB

    hipMemsetAsync(cnt, 0, 8 * sizeof(int), stream);
    cvt_x_kernel<<<2048, 256, 0, stream>>>(x, xbf);
    transpose_cvt_kernel<<<dim3(32, 8, 8), 256, 0, stream>>>(W1, w1t, 512, 2048);
    transpose_cvt_kernel<<<dim3(8, 32, 8), 256, 0, stream>>>(W2, w2t, 2048, 512);
    router_kernel<<<256, 256, 0, stream>>>(x, Wg, gate, list, cnt, pprob);
    gemm1_kernel<<<dim3(16, 64, 8), 256, 0, stream>>>(xbf, w1t, b1, list, cnt, hbf);
    gemm2_kernel<<<dim3(4, 64, 8), 256, 0, stream>>>(hbf, w2t, b2, list, cnt, gate, out);
    lb_kernel<<<1, 64, 0, stream>>>(pprob, cnt, out + (size_t)NTOK * H);
}